// Round 3
// baseline (2990.902 us; speedup 1.0000x reference)
//
#include <hip/hip_runtime.h>

#define TT 512
#define BB 64
#define EE 300
#define HH 1024
#define GG 4096
#define NSLOT 33   // h ring slots: drift <= ~2 steps, so no WAR; stale L2 evicted

typedef _Float16 f16x8 __attribute__((ext_vector_type(8)));
typedef float f32x4 __attribute__((ext_vector_type(4)));

// Workspace layout (bytes):
//   flags  @0, 1 KB                      per-block step flags
//   hbuf   @1024, NSLOT x 131072        h ring, f16, [kb32][quad4][b64][j8]
//   mask   @off_mask, 512*64*4           [t][b] f32
//   xA     @off_xA, 512*20480*2          x in MFMA-A layout [t][kb10][quad][b][j] f16
// total ~25.4 MB

__device__ __forceinline__ float sigmf(float x) {
    return __fdividef(1.0f, 1.0f + __expf(-x));
}
__device__ __forceinline__ float tanhsf(float x) {
    float e = __expf(-2.0f * fabsf(x));
    float r = __fdividef(1.0f - e, 1.0f + e);
    return copysignf(r, x);
}

__global__ void mask_kernel(const int* __restrict__ seq, float* __restrict__ maskf) {
    int idx = blockIdx.x * 256 + threadIdx.x;   // covers 512*64
    int t = idx >> 6, b = idx & 63;
    maskf[idx] = (seq[b * TT + t] != 0) ? 1.0f : 0.0f;
}

// xA[t][kb][quad][b][j] = f16(emb[seq[b][t]][e]), e = kb*32+quad*8+j, 0-pad e>=300
__global__ __launch_bounds__(256)
void xgather_kernel(const float* __restrict__ emb, const int* __restrict__ seq,
                    _Float16* __restrict__ xA) {
    __shared__ float xrow[64 * 305];
    const int t = blockIdx.x, tid = threadIdx.x;
    const int r = tid >> 2, sub = tid & 3;
    const int row = seq[r * TT + t];
    for (int e = sub; e < EE; e += 4)
        xrow[r * 305 + e] = emb[row * EE + e];
    __syncthreads();
    unsigned int* dst = (unsigned int*)(xA + (size_t)t * 20480);
    for (int idx = tid; idx < 10240; idx += 256) {
        int el = idx << 1;
        int j = el & 7, b = (el >> 3) & 63, quad = (el >> 9) & 3, kb = el >> 11;
        int e = (kb << 5) + (quad << 3) + j;
        union { _Float16 h[2]; unsigned int u; } pk;
        pk.h[0] = (e < EE)     ? (_Float16)xrow[b * 305 + e]     : (_Float16)0.f;
        pk.h[1] = (e + 1 < EE) ? (_Float16)xrow[b * 305 + e + 1] : (_Float16)0.f;
        dst[idx] = pk.u;
    }
}

// Persistent LSTM, one dispatch, 512 steps. 256 WGs x 512 thr (1/CU, 86KB LDS).
// r9: r6 source restored VERBATIM (r7 schedule reorder: -2x; r8 register
// hoist of B-frags: -11%; both with bit-identical memory counters -> the
// step time is a lockstep handshake equilibrium, sensitive to the schedule
// around the poll; pre-poll path is load-bearing and must not be touched).
// SINGLE change vs r6: S5 barrier removed. tid<64 == wave 0 does all h
// publish stores AND the flag store, so a wave-local s_waitcnt vmcnt(0)
// between them gives the same ordering S5 provided; waves 1-7 drop one
// barrier/step and the flag fires ~300cy earlier. Pre-poll schedule
// (maskf load, in-loop ds_read of B-frags, x.W) is byte-identical to r6.
__global__ __launch_bounds__(512, 2)
void lstm_kernel(const _Float16* __restrict__ xA, const float* __restrict__ rk,
                 const float* __restrict__ wk, const float* __restrict__ bias,
                 const float* __restrict__ maskf, _Float16* __restrict__ hbuf,
                 unsigned int* __restrict__ flags, float* __restrict__ out) {
    __shared__ _Float16 RbL[16384];   // [kb32][quad][c16][j8] B-frags of R
    __shared__ _Float16 WbL[5120];    // [kb10][quad][c16][j8] B-frags of W
    __shared__ float zb[8704];        // [8w][16c] rows, stride 68 (bank-safe)
    __shared__ float cs[2048];        // 256 used; padding forces 1 block/CU
    __shared__ _Float16 hshh[256];    // f16 publish staging [b][uu]
    const int tid = threadIdx.x;
    const int lane = tid & 63;
    const int w = tid >> 6;
    const int p = blockIdx.x;
    const int p4 = p << 2;
    const int cc = lane & 15, quad = lane >> 4;

    // pack R slice (k x 16 cols) into B-fragment order, f16, once
    for (int i = tid; i < 16384; i += 512) {
        int k = i >> 4, c = i & 15;
        float v = rk[k * GG + ((c >> 2) << 10) + p4 + (c & 3)];
        RbL[((k >> 5) << 9) + (((k >> 3) & 3) << 7) + (c << 3) + (k & 7)] = (_Float16)v;
    }
    for (int i = tid; i < 5120; i += 512) {
        int e = i >> 4, c = i & 15;
        float v = (e < EE) ? wk[e * GG + ((c >> 2) << 10) + p4 + (c & 3)] : 0.f;
        WbL[((e >> 5) << 9) + (((e >> 3) & 3) << 7) + (c << 3) + (e & 7)] = (_Float16)v;
    }
    if (tid < 256) cs[tid] = 0.f;
    float bb[4];
    if (w < 4) {
#pragma unroll
        for (int gt = 0; gt < 4; ++gt)
            bb[gt] = bias[(gt << 10) + p4 + w];
    }
    int slot = 0, nslot = 1;
    float hown = 0.0f;
    const int fidx = (w << 5) + (lane & 31);   // wave w's producers: p in [32w,32w+32)
    const f16x8* RbH = (const f16x8*)RbL;
    const f16x8* WbH = (const f16x8*)WbL;
    __syncthreads();

    for (int t = 0; t < TT; ++t) {
        float m = maskf[(t << 6) + lane];
        f32x4 acc[4];
#pragma unroll
        for (int mt = 0; mt < 4; ++mt) acc[mt] = (f32x4){0.f, 0.f, 0.f, 0.f};

        // ---- x.W part: no h dependency, runs before/through the wait ----
        const f16x8* xA8 = (const f16x8*)(xA + (size_t)t * 20480);
        {
            int kb = w;
            f16x8 bf = WbH[(kb << 6) + (quad << 4) + cc];
#pragma unroll
            for (int mt = 0; mt < 4; ++mt) {
                f16x8 af = xA8[(kb << 8) + (quad << 6) + (mt << 4) + cc];
                acc[mt] = __builtin_amdgcn_mfma_f32_16x16x32_f16(af, bf, acc[mt], 0, 0, 0);
            }
        }
        if (w < 2) {
            int kb = 8 + w;
            f16x8 bf = WbH[(kb << 6) + (quad << 4) + cc];
#pragma unroll
            for (int mt = 0; mt < 4; ++mt) {
                f16x8 af = xA8[(kb << 8) + (quad << 6) + (mt << 4) + cc];
                acc[mt] = __builtin_amdgcn_mfma_f32_16x16x32_f16(af, bf, acc[mt], 0, 0, 0);
            }
        }

        // ---- wait: my 32 producers must have published h^t ----
        if (t > 0) {
            unsigned int tgt = (unsigned int)t;
            while (!__all((int)(__hip_atomic_load(flags + fidx, __ATOMIC_RELAXED,
                                                  __HIP_MEMORY_SCOPE_AGENT) >= tgt)))
                __builtin_amdgcn_s_sleep(1);
        }
        __builtin_amdgcn_sched_barrier(0);   // keep h loads after the wait

        // ---- recurrent h.R: wave w owns k in [128w,128w+128) = kb 4w..4w+3 ----
        const f16x8* hA8 = (const f16x8*)(hbuf + (size_t)slot * 65536);
#pragma unroll
        for (int kc = 0; kc < 4; ++kc) {
            int kb = (w << 2) + kc;
            f16x8 bf = RbH[(kb << 6) + (quad << 4) + cc];
#pragma unroll
            for (int mt = 0; mt < 4; ++mt) {
                f16x8 af = hA8[(kb << 8) + (quad << 6) + (mt << 4) + cc];
                acc[mt] = __builtin_amdgcn_mfma_f32_16x16x32_f16(af, bf, acc[mt], 0, 0, 0);
            }
        }
        // D layout: col c = lane&15, b = 16*mt + quad*4 + reg
#pragma unroll
        for (int mt = 0; mt < 4; ++mt)
            *(f32x4*)(zb + ((w << 4) + cc) * 68 + (mt << 4) + (quad << 2)) = acc[mt];
        __syncthreads();                               // S3: partials done
        if (w < 4) {
            float z[4];
#pragma unroll
            for (int gt = 0; gt < 4; ++gt) {
                int c = (gt << 2) + w;
                float s = bb[gt];
#pragma unroll
                for (int wp = 0; wp < 8; ++wp) s += zb[((wp << 4) + c) * 68 + lane];
                z[gt] = s;
            }
            float fi = sigmf(z[0]);
            float ff = sigmf(z[1]);
            float fg = tanhsf(z[2]);
            float fo = sigmf(z[3]);
            float co = cs[(w << 6) + lane];
            float cn = fmaf(ff, co, fi * fg);
            cn = fmaf(m, cn - co, co);                 // masked c update
            cs[(w << 6) + lane] = cn;
            float hc = fo * tanhsf(cn);
            hown = fmaf(m, hc - hown, hown);           // masked h update (f32 local)
            hshh[(lane << 2) + w] = (_Float16)hown;
        }
        __syncthreads();                               // S4: hshh ready
        if (tid < 64) {                                // publish 4 f16 (8 B) per batch
            unsigned long long hv = ((const unsigned long long*)hshh)[lane];
            size_t el = (size_t)nslot * 65536 + ((size_t)(p >> 3) << 11) +
                        ((size_t)((p >> 1) & 3) << 9) + (lane << 3) + ((p & 1) << 2);
            __hip_atomic_store((unsigned long long*)(hbuf + el), hv,
                               __ATOMIC_RELAXED, __HIP_MEMORY_SCOPE_AGENT);
            // wave-local ordering: h stores drained before flag (replaces S5)
            asm volatile("s_waitcnt vmcnt(0)" ::: "memory");
            if (tid == 0)
                __hip_atomic_store(flags + p, (unsigned int)(t + 1),
                                   __ATOMIC_RELAXED, __HIP_MEMORY_SCOPE_AGENT);
        }
        slot = nslot;
        nslot = (nslot + 1 == NSLOT) ? 0 : nslot + 1;
    }
    // final h -> out (f32 path, hown is exact f32 state)
    if (w < 4) zb[(w << 6) + lane] = hown;
    __syncthreads();
    if (tid < 64) {
        float4 v = make_float4(zb[tid], zb[64 + tid], zb[128 + tid], zb[192 + tid]);
        *(float4*)(out + tid * HH + p4) = v;
    }
}

extern "C" void kernel_launch(void* const* d_in, const int* in_sizes, int n_in,
                              void* d_out, int out_size, void* d_ws, size_t ws_size,
                              hipStream_t stream) {
    const float* emb  = (const float*)d_in[0];
    const float* wk   = (const float*)d_in[1];
    const float* rk   = (const float*)d_in[2];
    const float* bias = (const float*)d_in[3];
    const int*   seq  = (const int*)d_in[4];
    float* out = (float*)d_out;
    char* ws = (char*)d_ws;

    const size_t off_hbuf = 1024;
    const size_t off_mask = off_hbuf + (size_t)NSLOT * 131072;   // f16 slots, 128 KB
    const size_t off_xA   = off_mask + 131072;
    unsigned int* flags = (unsigned int*)ws;
    _Float16* hbuf  = (_Float16*)(ws + off_hbuf);
    float*    maskf = (float*)(ws + off_mask);
    _Float16* xA    = (_Float16*)(ws + off_xA);

    // zero flags + hbuf slot 0 (contiguous prefix); ws is re-poisoned each call
    hipMemsetAsync(ws, 0, off_hbuf + 131072, stream);
    mask_kernel<<<128, 256, 0, stream>>>(seq, maskf);
    xgather_kernel<<<TT, 256, 0, stream>>>(emb, seq, xA);
    lstm_kernel<<<256, 512, 0, stream>>>(xA, rk, wk, bias, maskf, hbuf, flags, out);
}

// Round 6
// 1899.875 us; speedup vs baseline: 1.5743x; 1.5743x over previous
//
#include <hip/hip_runtime.h>

#define TT 512
#define BB 64
#define EE 300
#define HH 1024
#define GG 4096
#define NSLOT 33   // h ring slots: drift <= ~2 steps, so no WAR; stale L2 evicted

typedef _Float16 f16x8 __attribute__((ext_vector_type(8)));
typedef float f32x4 __attribute__((ext_vector_type(4)));

// Workspace layout (bytes):
//   flags  @0, 1 KB                      per-block step flags
//   hbuf   @1024, NSLOT x 131072        h ring, f16, [kb32][quad4][b64][j8]
//   mask   @off_mask, 512*64*4           [t][b] f32
//   xA     @off_xA, 512*20480*2          x in MFMA-A layout [t][kb10][quad][b][j] f16
// total ~25.4 MB

__device__ __forceinline__ float sigmf(float x) {
    return __fdividef(1.0f, 1.0f + __expf(-x));
}
__device__ __forceinline__ float tanhsf(float x) {
    float e = __expf(-2.0f * fabsf(x));
    float r = __fdividef(1.0f - e, 1.0f + e);
    return copysignf(r, x);
}

__global__ void mask_kernel(const int* __restrict__ seq, float* __restrict__ maskf) {
    int idx = blockIdx.x * 256 + threadIdx.x;   // covers 512*64
    int t = idx >> 6, b = idx & 63;
    maskf[idx] = (seq[b * TT + t] != 0) ? 1.0f : 0.0f;
}

// xA[t][kb][quad][b][j] = f16(emb[seq[b][t]][e]), e = kb*32+quad*8+j, 0-pad e>=300
__global__ __launch_bounds__(256)
void xgather_kernel(const float* __restrict__ emb, const int* __restrict__ seq,
                    _Float16* __restrict__ xA) {
    __shared__ float xrow[64 * 305];
    const int t = blockIdx.x, tid = threadIdx.x;
    const int r = tid >> 2, sub = tid & 3;
    const int row = seq[r * TT + t];
    for (int e = sub; e < EE; e += 4)
        xrow[r * 305 + e] = emb[row * EE + e];
    __syncthreads();
    unsigned int* dst = (unsigned int*)(xA + (size_t)t * 20480);
    for (int idx = tid; idx < 10240; idx += 256) {
        int el = idx << 1;
        int j = el & 7, b = (el >> 3) & 63, quad = (el >> 9) & 3, kb = el >> 11;
        int e = (kb << 5) + (quad << 3) + j;
        union { _Float16 h[2]; unsigned int u; } pk;
        pk.h[0] = (e < EE)     ? (_Float16)xrow[b * 305 + e]     : (_Float16)0.f;
        pk.h[1] = (e + 1 < EE) ? (_Float16)xrow[b * 305 + e + 1] : (_Float16)0.f;
        dst[idx] = pk.u;
    }
}

// Persistent LSTM, one dispatch, 512 steps. 256 WGs x 512 thr (1/CU, 86KB LDS).
// r12: THIRD submission of the verbatim r6 artifact. Rounds 4 and 5 both
// died with "MI355X container failed twice" — broker/acquisition failure,
// no kernel verdict produced. This exact schedule ran clean in round 0 of
// this session (1882.4 us; five dispatches 1827-1831 us, no outliers) and
// in the prior session (1880.0 us); only comments differ. Not a kernel bug.
// Session ledger of traffic-identical schedule edits:
//   r7 (x.W off pre-poll path, S5 removed, wave-7 publisher): 3650 us (-94%)
//   r8 (B-frags hoisted to registers, r6 ordering kept):      2137 us (-14%)
//   r9 (S5 -> wave-local vmcnt(0), pre-poll path identical):  2991 us (-59%,
//       plus a 33.7ms near-livelock outlier with FETCH +60MB = spin storm)
// Conclusion: the 256-block lockstep handshake sits at a sharp equilibrium.
// Elements that look like overhead are load-bearing throttles:
//   - pre-poll x.W + in-loop ds_read of B-frags: delay poll arrival so flags
//     are already set when waves get there (late-arrival = near-zero spin);
//   - S5: parks waves 1-7 during the publish drain (publish gets the vmem
//     pipe exclusively, flag visible sooner) AND delays their entry into
//     step t+1 (poll arrival stays late).
// Any edit that shortens the pre-poll path or unthrottles the publish window
// worsens the global equilibrium. Do not touch the loop schedule.
__global__ __launch_bounds__(512, 2)
void lstm_kernel(const _Float16* __restrict__ xA, const float* __restrict__ rk,
                 const float* __restrict__ wk, const float* __restrict__ bias,
                 const float* __restrict__ maskf, _Float16* __restrict__ hbuf,
                 unsigned int* __restrict__ flags, float* __restrict__ out) {
    __shared__ _Float16 RbL[16384];   // [kb32][quad][c16][j8] B-frags of R
    __shared__ _Float16 WbL[5120];    // [kb10][quad][c16][j8] B-frags of W
    __shared__ float zb[8704];        // [8w][16c] rows, stride 68 (bank-safe)
    __shared__ float cs[2048];        // 256 used; padding forces 1 block/CU
    __shared__ _Float16 hshh[256];    // f16 publish staging [b][uu]
    const int tid = threadIdx.x;
    const int lane = tid & 63;
    const int w = tid >> 6;
    const int p = blockIdx.x;
    const int p4 = p << 2;
    const int cc = lane & 15, quad = lane >> 4;

    // pack R slice (k x 16 cols) into B-fragment order, f16, once
    for (int i = tid; i < 16384; i += 512) {
        int k = i >> 4, c = i & 15;
        float v = rk[k * GG + ((c >> 2) << 10) + p4 + (c & 3)];
        RbL[((k >> 5) << 9) + (((k >> 3) & 3) << 7) + (c << 3) + (k & 7)] = (_Float16)v;
    }
    for (int i = tid; i < 5120; i += 512) {
        int e = i >> 4, c = i & 15;
        float v = (e < EE) ? wk[e * GG + ((c >> 2) << 10) + p4 + (c & 3)] : 0.f;
        WbL[((e >> 5) << 9) + (((e >> 3) & 3) << 7) + (c << 3) + (e & 7)] = (_Float16)v;
    }
    if (tid < 256) cs[tid] = 0.f;
    float bb[4];
    if (w < 4) {
#pragma unroll
        for (int gt = 0; gt < 4; ++gt)
            bb[gt] = bias[(gt << 10) + p4 + w];
    }
    int slot = 0, nslot = 1;
    float hown = 0.0f;
    const int fidx = (w << 5) + (lane & 31);   // wave w's producers: p in [32w,32w+32)
    const f16x8* RbH = (const f16x8*)RbL;
    const f16x8* WbH = (const f16x8*)WbL;
    __syncthreads();

    for (int t = 0; t < TT; ++t) {
        float m = maskf[(t << 6) + lane];
        f32x4 acc[4];
#pragma unroll
        for (int mt = 0; mt < 4; ++mt) acc[mt] = (f32x4){0.f, 0.f, 0.f, 0.f};

        // ---- x.W part: no h dependency, runs before/through the wait ----
        const f16x8* xA8 = (const f16x8*)(xA + (size_t)t * 20480);
        {
            int kb = w;
            f16x8 bf = WbH[(kb << 6) + (quad << 4) + cc];
#pragma unroll
            for (int mt = 0; mt < 4; ++mt) {
                f16x8 af = xA8[(kb << 8) + (quad << 6) + (mt << 4) + cc];
                acc[mt] = __builtin_amdgcn_mfma_f32_16x16x32_f16(af, bf, acc[mt], 0, 0, 0);
            }
        }
        if (w < 2) {
            int kb = 8 + w;
            f16x8 bf = WbH[(kb << 6) + (quad << 4) + cc];
#pragma unroll
            for (int mt = 0; mt < 4; ++mt) {
                f16x8 af = xA8[(kb << 8) + (quad << 6) + (mt << 4) + cc];
                acc[mt] = __builtin_amdgcn_mfma_f32_16x16x32_f16(af, bf, acc[mt], 0, 0, 0);
            }
        }

        // ---- wait: my 32 producers must have published h^t ----
        if (t > 0) {
            unsigned int tgt = (unsigned int)t;
            while (!__all((int)(__hip_atomic_load(flags + fidx, __ATOMIC_RELAXED,
                                                  __HIP_MEMORY_SCOPE_AGENT) >= tgt)))
                __builtin_amdgcn_s_sleep(1);
        }
        __builtin_amdgcn_sched_barrier(0);   // keep h loads after the wait

        // ---- recurrent h.R: wave w owns k in [128w,128w+128) = kb 4w..4w+3 ----
        const f16x8* hA8 = (const f16x8*)(hbuf + (size_t)slot * 65536);
#pragma unroll
        for (int kc = 0; kc < 4; ++kc) {
            int kb = (w << 2) + kc;
            f16x8 bf = RbH[(kb << 6) + (quad << 4) + cc];
#pragma unroll
            for (int mt = 0; mt < 4; ++mt) {
                f16x8 af = hA8[(kb << 8) + (quad << 6) + (mt << 4) + cc];
                acc[mt] = __builtin_amdgcn_mfma_f32_16x16x32_f16(af, bf, acc[mt], 0, 0, 0);
            }
        }
        // D layout: col c = lane&15, b = 16*mt + quad*4 + reg
#pragma unroll
        for (int mt = 0; mt < 4; ++mt)
            *(f32x4*)(zb + ((w << 4) + cc) * 68 + (mt << 4) + (quad << 2)) = acc[mt];
        __syncthreads();                               // S3: partials done
        if (w < 4) {
            float z[4];
#pragma unroll
            for (int gt = 0; gt < 4; ++gt) {
                int c = (gt << 2) + w;
                float s = bb[gt];
#pragma unroll
                for (int wp = 0; wp < 8; ++wp) s += zb[((wp << 4) + c) * 68 + lane];
                z[gt] = s;
            }
            float fi = sigmf(z[0]);
            float ff = sigmf(z[1]);
            float fg = tanhsf(z[2]);
            float fo = sigmf(z[3]);
            float co = cs[(w << 6) + lane];
            float cn = fmaf(ff, co, fi * fg);
            cn = fmaf(m, cn - co, co);                 // masked c update
            cs[(w << 6) + lane] = cn;
            float hc = fo * tanhsf(cn);
            hown = fmaf(m, hc - hown, hown);           // masked h update (f32 local)
            hshh[(lane << 2) + w] = (_Float16)hown;
        }
        __syncthreads();                               // S4: hshh ready
        if (tid < 64) {                                // publish 4 f16 (8 B) per batch
            unsigned long long hv = ((const unsigned long long*)hshh)[lane];
            size_t el = (size_t)nslot * 65536 + ((size_t)(p >> 3) << 11) +
                        ((size_t)((p >> 1) & 3) << 9) + (lane << 3) + ((p & 1) << 2);
            __hip_atomic_store((unsigned long long*)(hbuf + el), hv,
                               __ATOMIC_RELAXED, __HIP_MEMORY_SCOPE_AGENT);
        }
        __syncthreads();                               // S5: vmcnt(0), h visible
        if (tid == 0)
            __hip_atomic_store(flags + p, (unsigned int)(t + 1),
                               __ATOMIC_RELAXED, __HIP_MEMORY_SCOPE_AGENT);
        slot = nslot;
        nslot = (nslot + 1 == NSLOT) ? 0 : nslot + 1;
    }
    // final h -> out (f32 path, hown is exact f32 state)
    if (w < 4) zb[(w << 6) + lane] = hown;
    __syncthreads();
    if (tid < 64) {
        float4 v = make_float4(zb[tid], zb[64 + tid], zb[128 + tid], zb[192 + tid]);
        *(float4*)(out + tid * HH + p4) = v;
    }
}

extern "C" void kernel_launch(void* const* d_in, const int* in_sizes, int n_in,
                              void* d_out, int out_size, void* d_ws, size_t ws_size,
                              hipStream_t stream) {
    const float* emb  = (const float*)d_in[0];
    const float* wk   = (const float*)d_in[1];
    const float* rk   = (const float*)d_in[2];
    const float* bias = (const float*)d_in[3];
    const int*   seq  = (const int*)d_in[4];
    float* out = (float*)d_out;
    char* ws = (char*)d_ws;

    const size_t off_hbuf = 1024;
    const size_t off_mask = off_hbuf + (size_t)NSLOT * 131072;   // f16 slots, 128 KB
    const size_t off_xA   = off_mask + 131072;
    unsigned int* flags = (unsigned int*)ws;
    _Float16* hbuf  = (_Float16*)(ws + off_hbuf);
    float*    maskf = (float*)(ws + off_mask);
    _Float16* xA    = (_Float16*)(ws + off_xA);

    // zero flags + hbuf slot 0 (contiguous prefix); ws is re-poisoned each call
    hipMemsetAsync(ws, 0, off_hbuf + 131072, stream);
    mask_kernel<<<128, 256, 0, stream>>>(seq, maskf);
    xgather_kernel<<<TT, 256, 0, stream>>>(emb, seq, xA);
    lstm_kernel<<<256, 512, 0, stream>>>(xA, rk, wk, bias, maskf, hbuf, flags, out);
}